// Round 7
// baseline (3237.704 us; speedup 1.0000x reference)
//
#include <hip/hip_runtime.h>
#include <math.h>

typedef short  s8v __attribute__((ext_vector_type(8)));   // 8 bf16 (4 VGPRs)
typedef float  f4v __attribute__((ext_vector_type(4)));
typedef unsigned int u4v __attribute__((ext_vector_type(4)));
typedef unsigned long long ull;

#define S_LEN 512
#define BATCH 64
#define HID   512
#define TPB   256

// ---------------- fast-path workspace layout ----------------
// weights (bf16 hi/lo), xe bf16, tagged h records.
// h record = 8B {2 x bf16 | tag = tick+1}, layout [slot][b 64][rec 256]
#define WI0H_OFF 0L
#define WI0L_OFF 786432L
#define WH0H_OFF 1572864L
#define WH0L_OFF 3145728L
#define WI1H_OFF 4718592L
#define WI1L_OFF 6291456L
#define WH1H_OFF 7864320L
#define WH1L_OFF 9437184L
#define XEB_OFF  11010048L                   // xe bf16 [t*64+b][256]
#define H0R_OFF  27787264L                   // 512 slots x 16384 ull
#define H1R_OFF  94896128L                   // 4 slots x 16384 ull (ring, lag>=3 proof)
#define NEED_FAST 95420416L

// ---------------- fallback (fence path, R1) layout ----------------
#define BAR_BYTES   4096
#define HBUF_BYTES  (HID*BATCH*4)
#define A_OFF       BAR_BYTES
#define B_OFF       (A_OFF + 2*HBUF_BYTES)
#define XE_OFF      (B_OFF + 2*HBUF_BYTES)
#define XE_BYTES    ((size_t)S_LEN*64*BATCH*16)

__device__ __forceinline__ float fexp2(float x){ return __builtin_amdgcn_exp2f(x); }
__device__ __forceinline__ float frcp (float x){ return __builtin_amdgcn_rcpf(x); }
__device__ __forceinline__ float sigm (float x){ return frcp(1.f + fexp2(-1.44269504089f*x)); }
__device__ __forceinline__ float tanhx(float x){ return 1.f - 2.f*frcp(1.f + fexp2(2.88539008178f*x)); }
__device__ __forceinline__ float sigmoid_f(float v){ return 1.0f/(1.0f + expf(-v)); }

__device__ __forceinline__ unsigned short f2bf(float f){
  unsigned int u = __float_as_uint(f);
  u = u + 0x7FFFu + ((u >> 16) & 1u);          // RNE
  return (unsigned short)(u >> 16);
}
__device__ __forceinline__ float bf2f(unsigned short s){
  return __uint_as_float(((unsigned int)s) << 16);
}

// =====================================================================
// Phase A kernels
// =====================================================================
__global__ void wcvt_kernel(const float* __restrict__ Wih0, const float* __restrict__ Whh0,
                            const float* __restrict__ Wih1, const float* __restrict__ Whh1,
                            char* __restrict__ ws)
{
  int idx = blockIdx.x * TPB + threadIdx.x;    // 2,752,512 total
  const float* src; long hi_off, lo_off; int pos;
  if (idx < 393216)       { src = Wih0; pos = idx;           hi_off = WI0H_OFF; lo_off = WI0L_OFF; }
  else if (idx < 1179648) { src = Whh0; pos = idx - 393216;  hi_off = WH0H_OFF; lo_off = WH0L_OFF; }
  else if (idx < 1966080) { src = Wih1; pos = idx - 1179648; hi_off = WI1H_OFF; lo_off = WI1L_OFF; }
  else                    { src = Whh1; pos = idx - 1966080; hi_off = WH1H_OFF; lo_off = WH1L_OFF; }
  float w = src[pos];
  unsigned short h = f2bf(w);
  unsigned short l = f2bf(w - bf2f(h));
  ((unsigned short*)(ws + hi_off))[pos] = h;
  ((unsigned short*)(ws + lo_off))[pos] = l;
}

__global__ void gather_xe_bf_kernel(const int* __restrict__ x,
                                    const float* __restrict__ emb,
                                    char* __restrict__ ws)
{
  int idx = blockIdx.x * TPB + threadIdx.x;    // 2,097,152 = 32768 n * 64 k4
  int k4 = idx & 63;
  int n  = idx >> 6;
  int t = n >> 6, b = n & 63;
  int tok = x[b * S_LEN + t];
  float4 v = make_float4(0.f,0.f,0.f,0.f);
  if (tok != 0) v = ((const float4*)emb)[(size_t)tok * 64 + k4];
  unsigned int lo = (unsigned int)f2bf(v.x) | ((unsigned int)f2bf(v.y) << 16);
  unsigned int hi = (unsigned int)f2bf(v.z) | ((unsigned int)f2bf(v.w) << 16);
  ((uint2*)(ws + XEB_OFF))[(long)n * 64 + k4] = make_uint2(lo, hi);
}

// =====================================================================
// scan body: one wave's role for the whole 512-tick loop.
// ROLE: 0 = xe input (plain loads), 1 = self-layer hidden (slot (t-1)&mask, want t),
//       2 = cross h0 input (slot t, want t+1)
// Tagged-record h: [slot][b][rec], rec = 8B {2 bf16 | tag}. Two-phase wait:
// phase-1 one 16B poll load/lane covers all 128 rec-rows of the wave's slice;
// phase-2 bulk 16B loads with tag revalidation (correctness never depends on
// phase-1 — tags ride with the data).
// =====================================================================
template<int NKS, int ROLE>
__device__ __forceinline__ void scan_body(
    int isL1, int rowWG, int bh, int wave, int lane, int tid, int j0, int b0,
    const s8v* __restrict__ Whi, const s8v* __restrict__ Wlo, int AKs, int k0s,
    const s8v* __restrict__ xsrc,
    const ull* __restrict__ rsrc, int slotMask,
    const float* __restrict__ bih, const float* __restrict__ bhh,
    ull* __restrict__ rout, int outMask,
    f4v* __restrict__ part)
{
  const int quad = lane >> 4, col = lane & 15;

  // ---- A fragments (hi + lo), resident across all 512 ticks ----
  s8v ahi[3][NKS], alo[3][NKS];
  #pragma unroll
  for (int rt = 0; rt < 3; ++rt){
    const int row = rt*512 + j0 + col;
    #pragma unroll
    for (int ks = 0; ks < NKS; ++ks){
      const int e = row*AKs + k0s + ks*4 + quad;
      ahi[rt][ks] = Whi[e];
      alo[rt][ks] = Wlo[e];
    }
  }

  // ---- per-thread gate constants + persistent fp32 h (lane<32) ----
  float cr[4], cz[4], cnx[4], cnh[4], hp[4];
  #pragma unroll
  for (int r4 = 0; r4 < 4; ++r4){
    int j = j0 + wave*4 + r4;
    cr[r4]  = bih[j]      + bhh[j];
    cz[r4]  = bih[512+j]  + bhh[512+j];
    cnx[r4] = bih[1024+j];
    cnh[r4] = bhh[1024+j];
    hp[r4]  = 0.f;
  }

  for (int t = 0; t < S_LEN; ++t){
    f4v acc[3][2];
    #pragma unroll
    for (int rt = 0; rt < 3; ++rt){ acc[rt][0] = (f4v)0.f; acc[rt][1] = (f4v)0.f; }

    if (ROLE == 0){
      // ---- plain xe input (pre-converted, no tags) ----
      #pragma unroll
      for (int ct = 0; ct < 2; ++ct){
        const int nG = b0 + ct*16 + col;
        const long base = ((long)t*64 + nG)*32 + k0s + quad;
        s8v bf[NKS];
        #pragma unroll
        for (int ks = 0; ks < NKS; ++ks) bf[ks] = xsrc[base + ks*4];
        #pragma unroll
        for (int ks = 0; ks < NKS; ++ks)
          #pragma unroll
          for (int rt = 0; rt < 3; ++rt){
            acc[rt][ct] = __builtin_amdgcn_mfma_f32_16x16x32_bf16(ahi[rt][ks], bf[ks], acc[rt][ct], 0, 0, 0);
            acc[rt][ct] = __builtin_amdgcn_mfma_f32_16x16x32_bf16(alo[rt][ks], bf[ks], acc[rt][ct], 0, 0, 0);
          }
      }
    } else if ((ROLE != 1) || (t > 0)){
      const int slot = (ROLE == 1) ? ((t-1) & slotMask) : (t & slotMask);
      const unsigned want = (ROLE == 1) ? (unsigned)t : (unsigned)(t+1);
      const ull* sl = rsrc + (long)slot*16384;

      // ---- phase-1: one 16B poll load per lane (2 tagged recs); the 64
      // lanes' rec pairs tile the full 128 rec-rows of this wave's K slice ----
      {
        const ull* pp = sl + (long)(b0 + (lane & 31))*256 + (4*k0s + 2*lane);
        for (;;){
          u4v pv;
          asm volatile("global_load_dwordx4 %0, %1, off sc0 sc1\n\t"
                       "s_waitcnt vmcnt(0)"
                       : "=&v"(pv) : "v"(pp) : "memory");
          if (__all((pv.y == want) && (pv.w == want))) break;
          __builtin_amdgcn_s_sleep(2);
        }
      }

      // ---- phase-2: bulk 16B loads + tag revalidation ----
      #pragma unroll
      for (int ct = 0; ct < 2; ++ct){
        const int b = b0 + ct*16 + col;
        const ull* bb = sl + (long)b*256 + (4*k0s + 4*quad);
        s8v bf[NKS];
        for (;;){
          u4v q0[NKS], q1[NKS];
          #pragma unroll
          for (int ks = 0; ks < NKS; ++ks){
            const ull* a = bb + 16*ks;
            asm volatile("global_load_dwordx4 %0, %1, off sc0 sc1"
                         : "=&v"(q0[ks]) : "v"(a) : "memory");
            asm volatile("global_load_dwordx4 %0, %1, off sc0 sc1"
                         : "=&v"(q1[ks]) : "v"(a + 2) : "memory");
          }
          asm volatile("s_waitcnt vmcnt(0)" ::: "memory");
          bool ok = true;
          #pragma unroll
          for (int ks = 0; ks < NKS; ++ks)
            ok = ok && (q0[ks].y == want) && (q0[ks].w == want)
                    && (q1[ks].y == want) && (q1[ks].w == want);
          if (__all(ok)){
            #pragma unroll
            for (int ks = 0; ks < NKS; ++ks){
              u4v tv; tv.x = q0[ks].x; tv.y = q0[ks].z; tv.z = q1[ks].x; tv.w = q1[ks].z;
              bf[ks] = *(s8v*)&tv;
            }
            break;
          }
          __builtin_amdgcn_s_sleep(2);
        }
        #pragma unroll
        for (int ks = 0; ks < NKS; ++ks)
          #pragma unroll
          for (int rt = 0; rt < 3; ++rt){
            acc[rt][ct] = __builtin_amdgcn_mfma_f32_16x16x32_bf16(ahi[rt][ks], bf[ks], acc[rt][ct], 0, 0, 0);
            acc[rt][ct] = __builtin_amdgcn_mfma_f32_16x16x32_bf16(alo[rt][ks], bf[ks], acc[rt][ct], 0, 0, 0);
          }
      }
    }

    // ---- partials to LDS (double-buffered: one barrier per tick) ----
    const int pb = t & 1;
    #pragma unroll
    for (int rt = 0; rt < 3; ++rt)
      #pragma unroll
      for (int ct = 0; ct < 2; ++ct)
        part[((pb*4 + wave)*6 + rt*2 + ct)*64 + lane] = acc[rt][ct];
    __syncthreads();

    // ---- reduce + gate math + tagged 16B h store (wave = unit-group, lane<32 = b) ----
    if (lane < 32){
      const int b = lane;
      const int pl = wave*16 + (b & 15);
      const int ct = b >> 4;
      f4v sr = (f4v)0.f, sz = (f4v)0.f, snx = (f4v)0.f, snh = (f4v)0.f;
      #pragma unroll
      for (int w = 0; w < 4; ++w){
        const bool inpW = isL1 ? (w < 2) : (w >= 2);
        f4v g0 = part[((pb*4 + w)*6 + 0*2 + ct)*64 + pl];
        f4v g1 = part[((pb*4 + w)*6 + 1*2 + ct)*64 + pl];
        f4v g2 = part[((pb*4 + w)*6 + 2*2 + ct)*64 + pl];
        sr += g0; sz += g1;
        if (inpW) snx += g2; else snh += g2;
      }
      unsigned short hb[4];
      #pragma unroll
      for (int r4 = 0; r4 < 4; ++r4){
        float r = sigm(sr[r4] + cr[r4]);
        float z = sigm(sz[r4] + cz[r4]);
        float n = tanhx(snx[r4] + cnx[r4] + r*(snh[r4] + cnh[r4]));
        float h = n + z*(hp[r4] - n);
        hp[r4] = h;
        hb[r4] = f2bf(h);
      }
      const int slotw = t & outMask;
      const unsigned tg = (unsigned)(t + 1);
      u4v sv;
      sv.x = (unsigned)hb[0] | ((unsigned)hb[1] << 16); sv.y = tg;
      sv.z = (unsigned)hb[2] | ((unsigned)hb[3] << 16); sv.w = tg;
      ull* ob = rout + (long)slotw*16384 + (long)(b0 + b)*256 + (rowWG*8 + wave*2);
      asm volatile("global_store_dwordx4 %0, %1, off sc0 sc1" :: "v"(ob), "v"(sv) : "memory");
    }
    // no trailing barrier: next tick writes the other partial buffer
  }
}

// =====================================================================
// Persistent MFMA scan kernel: 128 WGs.
// wg 0..63: layer0, wg 64..127: layer1. lw=wg&63: rowWG=lw>>1, bh=lw&1.
// L0: waves 0-1 hidden (h0), waves 2-3 xe input. L1: waves 0-1 input (h0
// cross), waves 2-3 hidden (h1, 4-slot ring).
// =====================================================================
__global__ __launch_bounds__(TPB, 1) void gru_mfma_kernel(
    const float* __restrict__ bih0, const float* __restrict__ bhh0,
    const float* __restrict__ bih1, const float* __restrict__ bhh1,
    const float* __restrict__ Wfc,  const float* __restrict__ bfc,
    float* __restrict__ out, char* __restrict__ ws)
{
  __shared__ f4v part[3072];                   // 48 KB double-buffered partials

  const int tid  = threadIdx.x;
  const int wg   = blockIdx.x;
  const int lane = tid & 63;
  const int wave = tid >> 6;
  const int isL1 = (wg >= 64);
  const int lw   = wg & 63;
  const int rowWG = lw >> 1;
  const int bh    = lw & 1;
  const int j0 = rowWG * 16;
  const int b0 = bh * 32;

  const s8v* wi0h = (const s8v*)(ws + WI0H_OFF); const s8v* wi0l = (const s8v*)(ws + WI0L_OFF);
  const s8v* wh0h = (const s8v*)(ws + WH0H_OFF); const s8v* wh0l = (const s8v*)(ws + WH0L_OFF);
  const s8v* wi1h = (const s8v*)(ws + WI1H_OFF); const s8v* wi1l = (const s8v*)(ws + WI1L_OFF);
  const s8v* wh1h = (const s8v*)(ws + WH1H_OFF); const s8v* wh1l = (const s8v*)(ws + WH1L_OFF);
  const s8v* xeb = (const s8v*)(ws + XEB_OFF);
  const ull* h0r = (const ull*)(ws + H0R_OFF);
  const ull* h1r = (const ull*)(ws + H1R_OFF);
  ull* h0w = (ull*)(ws + H0R_OFF);
  ull* h1w = (ull*)(ws + H1R_OFF);

  if (!isL1){
    if (wave < 2)
      scan_body<8,1>(isL1, rowWG, bh, wave, lane, tid, j0, b0,
                     wh0h, wh0l, 64, wave*32, xeb, h0r, 0x3FFFFFFF,
                     bih0, bhh0, h0w, 0x3FFFFFFF, part);
    else
      scan_body<4,0>(isL1, rowWG, bh, wave, lane, tid, j0, b0,
                     wi0h, wi0l, 32, (wave-2)*16, xeb, h0r, 0x3FFFFFFF,
                     bih0, bhh0, h0w, 0x3FFFFFFF, part);
  } else {
    if (wave < 2)
      scan_body<8,2>(isL1, rowWG, bh, wave, lane, tid, j0, b0,
                     wi1h, wi1l, 64, wave*32, xeb, h0r, 0x3FFFFFFF,
                     bih1, bhh1, h1w, 3, part);
    else
      scan_body<8,1>(isL1, rowWG, bh, wave, lane, tid, j0, b0,
                     wh1h, wh1l, 64, (wave-2)*32, xeb, h1r, 3,
                     bih1, bhh1, h1w, 3, part);
  }

  // ---- epilogue FC: out[b] = sigmoid(h1_511 . Wfc + bfc), tag-validated ----
  if (wg == 64 && wave == 0){
    const ull* bb = h1r + 3L*16384 + (long)lane*256;   // slot 511&3, b = lane
    float acc = bfc[0];
    for (int c0 = 0; c0 < 256; c0 += 32){
      ull d[32];
      for (;;){
        #pragma unroll
        for (int i = 0; i < 32; ++i)
          d[i] = __hip_atomic_load(bb + c0 + i, __ATOMIC_RELAXED, __HIP_MEMORY_SCOPE_AGENT);
        bool ok = true;
        #pragma unroll
        for (int i = 0; i < 32; ++i) ok = ok && ((unsigned)(d[i] >> 32) == 512u);
        if (__all(ok)) break;
        __builtin_amdgcn_s_sleep(1);
      }
      #pragma unroll
      for (int i = 0; i < 32; ++i){
        unsigned lo = (unsigned)d[i];
        int u = (c0 + i) * 2;
        acc += bf2f((unsigned short)(lo & 0xFFFFu)) * Wfc[u]
             + bf2f((unsigned short)(lo >> 16))     * Wfc[u+1];
      }
    }
    out[lane] = sigm(acc);
  }
}

// =====================================================================
// FALLBACK (R1 fence path) — only if ws too small for the fast path.
// =====================================================================
__global__ void gather_xe_kernel(const int* __restrict__ x,
                                 const float* __restrict__ emb,
                                 float4* __restrict__ xe4)
{
  int idx = blockIdx.x * TPB + threadIdx.x;
  int b  = idx & 63;
  int k4 = (idx >> 6) & 63;
  int t  = idx >> 12;
  int tok = x[b * S_LEN + t];
  float4 v = make_float4(0.f, 0.f, 0.f, 0.f);
  if (tok != 0) v = ((const float4*)emb)[(size_t)tok * 64 + k4];
  xe4[idx] = v;
}

__device__ __forceinline__ void accum_vec(const float4* __restrict__ xin,
                                          const float4* __restrict__ w0,
                                          const float4* __restrict__ w1,
                                          const float4* __restrict__ w2,
                                          int n4, int lane,
                                          float& ar, float& az, float& an)
{
  #pragma unroll 4
  for (int k = 0; k < n4; ++k){
    float4 xv = xin[k * 64 + lane];
    float4 wr = w0[k], wz = w1[k], wn = w2[k];
    ar = fmaf(xv.x, wr.x, ar); az = fmaf(xv.x, wz.x, az); an = fmaf(xv.x, wn.x, an);
    ar = fmaf(xv.y, wr.y, ar); az = fmaf(xv.y, wz.y, az); an = fmaf(xv.y, wn.y, an);
    ar = fmaf(xv.z, wr.z, ar); az = fmaf(xv.z, wz.z, az); an = fmaf(xv.z, wn.z, an);
    ar = fmaf(xv.w, wr.w, ar); az = fmaf(xv.w, wz.w, az); an = fmaf(xv.w, wn.w, an);
  }
}

__device__ __forceinline__ void accum_emb(const int* __restrict__ x,
                                          const float* __restrict__ emb, int t,
                                          const float4* __restrict__ w0,
                                          const float4* __restrict__ w1,
                                          const float4* __restrict__ w2,
                                          int lane, float& ar, float& az, float& an)
{
  int tok = x[lane * S_LEN + t];
  const float4* erow = (const float4*)emb + (size_t)tok * 64;
  float m = (tok != 0) ? 1.0f : 0.0f;
  #pragma unroll 4
  for (int k = 0; k < 64; ++k){
    float4 xv = erow[k];
    float xx = xv.x*m, xy = xv.y*m, xz = xv.z*m, xw = xv.w*m;
    float4 wr = w0[k], wz = w1[k], wn = w2[k];
    ar = fmaf(xx, wr.x, ar); az = fmaf(xx, wz.x, az); an = fmaf(xx, wn.x, an);
    ar = fmaf(xy, wr.y, ar); az = fmaf(xy, wz.y, az); an = fmaf(xy, wn.y, an);
    ar = fmaf(xz, wr.z, ar); az = fmaf(xz, wz.z, az); an = fmaf(xz, wn.z, an);
    ar = fmaf(xw, wr.w, ar); az = fmaf(xw, wz.w, az); an = fmaf(xw, wn.w, an);
  }
}

__device__ __forceinline__ void stage_weights(float4* wlds, int tid, int j0, int kin4,
                                              const float* Wih, const float* Whh)
{
  const int per = 3 * (kin4 + 128);
  for (int idx = tid; idx < 4 * per; idx += TPB){
    int w = idx / per, rem = idx - w * per;
    int g = rem / (kin4 + 128), k = rem - g * (kin4 + 128);
    int row = g * HID + j0 + w;
    float4 v;
    if (k < kin4) v = ((const float4*)Wih)[(size_t)row * kin4 + k];
    else          v = ((const float4*)Whh)[(size_t)row * 128 + (k - kin4)];
    wlds[(w * 3 + g) * 256 + k] = v;
  }
}

__device__ __forceinline__ void barrier_tick(int* bar, int wg, int tid, int phase)
{
  __syncthreads();
  if (tid == 0){
    __builtin_amdgcn_fence(__ATOMIC_RELEASE, "agent");
    int* leaf = bar + 32 + (wg >> 4) * 32;
    int old = __hip_atomic_fetch_add(leaf, 1, __ATOMIC_ACQ_REL, __HIP_MEMORY_SCOPE_AGENT);
    if (old == phase * 16 + 15){
      __hip_atomic_fetch_add(bar, 1, __ATOMIC_ACQ_REL, __HIP_MEMORY_SCOPE_AGENT);
    }
    const int target = (phase + 1) * 16;
    while (__hip_atomic_load(bar, __ATOMIC_ACQUIRE, __HIP_MEMORY_SCOPE_AGENT) < target){
      __builtin_amdgcn_s_sleep(2);
    }
    __builtin_amdgcn_fence(__ATOMIC_ACQUIRE, "agent");
  }
  __syncthreads();
}

__device__ __forceinline__ void finish_store(const float4* __restrict__ hprev,
                                             float ar, float az, float anx, float anh,
                                             int lane, int j, float4* __restrict__ hout)
{
  float r  = sigmoid_f(ar);
  float zz = sigmoid_f(az);
  float n  = tanhf(fmaf(r, anh, anx));
  int fi = ((j >> 2) * 64 + lane) * 4 + (j & 3);
  float hhp = ((const float*)hprev)[fi];
  ((float*)hout)[fi] = fmaf(zz, hhp - n, n);
}

__global__ __launch_bounds__(TPB) void gru_persist_kernel(
    const int*   __restrict__ x,    const float* __restrict__ emb,
    const float* __restrict__ Wih0, const float* __restrict__ Whh0,
    const float* __restrict__ bih0, const float* __restrict__ bhh0,
    const float* __restrict__ Wih1, const float* __restrict__ Whh1,
    const float* __restrict__ bih1, const float* __restrict__ bhh1,
    const float* __restrict__ Wfc,  const float* __restrict__ bfc,
    float* __restrict__ out, int* __restrict__ bar,
    float4* __restrict__ A0, float4* __restrict__ A1,
    float4* __restrict__ B0, float4* __restrict__ B1,
    const float4* __restrict__ xe4, int use_xe)
{
  __shared__ float4 wlds[3072];
  const int tid  = threadIdx.x;
  const int wg   = blockIdx.x;
  const int lane = tid & 63;
  const int wave = tid >> 6;
  const bool isL1 = (wg >= 128);
  const int j0   = (isL1 ? wg - 128 : wg) * 4;
  const int kin4 = isL1 ? 128 : 64;

  stage_weights(wlds, tid, j0, kin4, isL1 ? Wih1 : Wih0, isL1 ? Whh1 : Whh0);
  __syncthreads();

  const int j = j0 + wave;
  const float* bih = isL1 ? bih1 : bih0;
  const float* bhh = isL1 ? bhh1 : bhh0;
  const float br  = bih[j]        + bhh[j];
  const float bz  = bih[j + 512]  + bhh[j + 512];
  const float bnx = bih[j + 1024];
  const float bnh = bhh[j + 1024];

  const float4* w0 = &wlds[(wave * 3 + 0) * 256];
  const float4* w1 = &wlds[(wave * 3 + 1) * 256];
  const float4* w2 = &wlds[(wave * 3 + 2) * 256];

  float4* A[2] = {A0, A1};
  float4* B[2] = {B0, B1};

  for (int t = 0; t <= S_LEN; ++t){
    if (!isL1){
      if (t < S_LEN){
        const float4* hprev = A[(t + 1) & 1];
        float ar = br, az = bz, anx = bnx, anh = bnh;
        if (use_xe) accum_vec(xe4 + (size_t)t * 4096, w0, w1, w2, 64, lane, ar, az, anx);
        else        accum_emb(x, emb, t, w0, w1, w2, lane, ar, az, anx);
        accum_vec(hprev, w0 + 64, w1 + 64, w2 + 64, 128, lane, ar, az, anh);
        finish_store(hprev, ar, az, anx, anh, lane, j, A[t & 1]);
      }
    } else if (t >= 1){
      const int u = t - 1;
      const float4* xin   = A[u & 1];
      const float4* hprev = B[(u + 1) & 1];
      float ar = br, az = bz, anx = bnx, anh = bnh;
      accum_vec(xin,   w0,       w1,       w2,       128, lane, ar, az, anx);
      accum_vec(hprev, w0 + 128, w1 + 128, w2 + 128, 128, lane, ar, az, anh);
      finish_store(hprev, ar, az, anx, anh, lane, j, B[u & 1]);
    }
    barrier_tick(bar, wg, tid, t);
  }

  if (wg == 0 && wave == 0){
    float acc = bfc[0];
    const float4* h1 = B[1];
    const float4* wf = (const float4*)Wfc;
    #pragma unroll 4
    for (int k = 0; k < 128; ++k){
      float4 hv = h1[k * 64 + lane];
      float4 wv = wf[k];
      acc = fmaf(hv.x, wv.x, acc); acc = fmaf(hv.y, wv.y, acc);
      acc = fmaf(hv.z, wv.z, acc); acc = fmaf(hv.w, wv.w, acc);
    }
    out[lane] = sigmoid_f(acc);
  }
}

extern "C" void kernel_launch(void* const* d_in, const int* in_sizes, int n_in,
                              void* d_out, int out_size, void* d_ws, size_t ws_size,
                              hipStream_t stream)
{
  (void)in_sizes; (void)n_in; (void)out_size;
  const int*   x    = (const int*)  d_in[0];
  const float* emb  = (const float*)d_in[1];
  const float* Wih0 = (const float*)d_in[2];
  const float* Whh0 = (const float*)d_in[3];
  const float* bih0 = (const float*)d_in[4];
  const float* bhh0 = (const float*)d_in[5];
  const float* Wih1 = (const float*)d_in[6];
  const float* Whh1 = (const float*)d_in[7];
  const float* bih1 = (const float*)d_in[8];
  const float* bhh1 = (const float*)d_in[9];
  const float* Wfc  = (const float*)d_in[10];
  const float* bfc  = (const float*)d_in[11];
  float* out = (float*)d_out;
  char* ws = (char*)d_ws;

  if (ws_size >= (size_t)NEED_FAST){
    // no sync memset needed: tagged records self-validate against 0xAA poison
    wcvt_kernel<<<2752512 / TPB, TPB, 0, stream>>>(Wih0, Whh0, Wih1, Whh1, ws);
    gather_xe_bf_kernel<<<2097152 / TPB, TPB, 0, stream>>>(x, emb, ws);
    gru_mfma_kernel<<<128, TPB, 0, stream>>>(bih0, bhh0, bih1, bhh1, Wfc, bfc, out, ws);
  } else {
    int*    bar = (int*)ws;
    float4* A0  = (float4*)(ws + A_OFF);
    float4* A1  = (float4*)(ws + A_OFF + HBUF_BYTES);
    float4* B0  = (float4*)(ws + B_OFF);
    float4* B1  = (float4*)(ws + B_OFF + HBUF_BYTES);
    float4* xe4 = (float4*)(ws + XE_OFF);
    const int use_xe = (ws_size >= (size_t)XE_OFF + XE_BYTES) ? 1 : 0;
    hipMemsetAsync(ws, 0, XE_OFF, stream);
    if (use_xe){
      gather_xe_kernel<<<(S_LEN * 64 * BATCH) / TPB, TPB, 0, stream>>>(x, emb, xe4);
    }
    gru_persist_kernel<<<256, TPB, 0, stream>>>(
        x, emb, Wih0, Whh0, bih0, bhh0, Wih1, Whh1, bih1, bhh1, Wfc, bfc,
        out, bar, A0, A1, B0, B1, xe4, use_xe);
  }
}

// Round 8
// 2680.654 us; speedup vs baseline: 1.2078x; 1.2078x over previous
//
#include <hip/hip_runtime.h>
#include <math.h>

typedef short  s8v __attribute__((ext_vector_type(8)));   // 8 bf16 (4 VGPRs)
typedef float  f4v __attribute__((ext_vector_type(4)));
typedef unsigned long long ull;

#define S_LEN 512
#define BATCH 64
#define HID   512
#define TPB   256

// ---------------- fast-path workspace layout ----------------
// weights (bf16 hi/lo), xe bf16, tagged h records, hint flags.
// h record = 8B {2 x bf16 | tag = tick+1}, layout [slot][rec 256][b 64]
#define WI0H_OFF 0L
#define WI0L_OFF 786432L
#define WH0H_OFF 1572864L
#define WH0L_OFF 3145728L
#define WI1H_OFF 4718592L
#define WI1L_OFF 6291456L
#define WH1H_OFF 7864320L
#define WH1L_OFF 9437184L
#define XEB_OFF  11010048L                   // xe bf16 [t*64+b][256]
#define H0R_OFF  27787264L                   // 512 slots x 16384 ull
#define H1R_OFF  94896128L                   // 4 slots x 16384 ull (ring, lag>=3 proof)
#define FLG_OFF  95420416L                   // [l][m][rep4] 128B lines, dword=rowWG
#define NEED_FAST 95422464L

// ---------------- fallback (fence path, R1) layout ----------------
#define BAR_BYTES   4096
#define HBUF_BYTES  (HID*BATCH*4)
#define A_OFF       BAR_BYTES
#define B_OFF       (A_OFF + 2*HBUF_BYTES)
#define XE_OFF      (B_OFF + 2*HBUF_BYTES)
#define XE_BYTES    ((size_t)S_LEN*64*BATCH*16)

__device__ __forceinline__ float fexp2(float x){ return __builtin_amdgcn_exp2f(x); }
__device__ __forceinline__ float frcp (float x){ return __builtin_amdgcn_rcpf(x); }
__device__ __forceinline__ float sigm (float x){ return frcp(1.f + fexp2(-1.44269504089f*x)); }
__device__ __forceinline__ float tanhx(float x){ return 1.f - 2.f*frcp(1.f + fexp2(2.88539008178f*x)); }
__device__ __forceinline__ float sigmoid_f(float v){ return 1.0f/(1.0f + expf(-v)); }

__device__ __forceinline__ unsigned short f2bf(float f){
  unsigned int u = __float_as_uint(f);
  u = u + 0x7FFFu + ((u >> 16) & 1u);          // RNE
  return (unsigned short)(u >> 16);
}
__device__ __forceinline__ float bf2f(unsigned short s){
  return __uint_as_float(((unsigned int)s) << 16);
}

// =====================================================================
// Phase A kernels
// =====================================================================
__global__ void wcvt_kernel(const float* __restrict__ Wih0, const float* __restrict__ Whh0,
                            const float* __restrict__ Wih1, const float* __restrict__ Whh1,
                            char* __restrict__ ws)
{
  int idx = blockIdx.x * TPB + threadIdx.x;    // 2,752,512 total
  const float* src; long hi_off, lo_off; int pos;
  if (idx < 393216)       { src = Wih0; pos = idx;           hi_off = WI0H_OFF; lo_off = WI0L_OFF; }
  else if (idx < 1179648) { src = Whh0; pos = idx - 393216;  hi_off = WH0H_OFF; lo_off = WH0L_OFF; }
  else if (idx < 1966080) { src = Wih1; pos = idx - 1179648; hi_off = WI1H_OFF; lo_off = WI1L_OFF; }
  else                    { src = Whh1; pos = idx - 1966080; hi_off = WH1H_OFF; lo_off = WH1L_OFF; }
  float w = src[pos];
  unsigned short h = f2bf(w);
  unsigned short l = f2bf(w - bf2f(h));
  ((unsigned short*)(ws + hi_off))[pos] = h;
  ((unsigned short*)(ws + lo_off))[pos] = l;
}

__global__ void gather_xe_bf_kernel(const int* __restrict__ x,
                                    const float* __restrict__ emb,
                                    char* __restrict__ ws)
{
  int idx = blockIdx.x * TPB + threadIdx.x;    // 2,097,152 = 32768 n * 64 k4
  int k4 = idx & 63;
  int n  = idx >> 6;
  int t = n >> 6, b = n & 63;
  int tok = x[b * S_LEN + t];
  float4 v = make_float4(0.f,0.f,0.f,0.f);
  if (tok != 0) v = ((const float4*)emb)[(size_t)tok * 64 + k4];
  unsigned int lo = (unsigned int)f2bf(v.x) | ((unsigned int)f2bf(v.y) << 16);
  unsigned int hi = (unsigned int)f2bf(v.z) | ((unsigned int)f2bf(v.w) << 16);
  ((uint2*)(ws + XEB_OFF))[(long)n * 64 + k4] = make_uint2(lo, hi);
}

// =====================================================================
// Sync primitives.
// Hint flags: flag[l][m][rep][rowWG] = completed ticks of that producer WG.
// Published WITHOUT store drain (tags in the data records remain ground
// truth); polled as one 128B broadcast line (lanes 0..31 = rowWG).
// =====================================================================
__device__ __forceinline__ void st_rec(ull* p, ull v){
  __hip_atomic_store(p, v, __ATOMIC_RELAXED, __HIP_MEMORY_SCOPE_AGENT);
}
__device__ __forceinline__ void hint_wait(const unsigned* fl, int lane, unsigned target){
  const unsigned* p = fl + (lane & 31);
  for (;;){
    unsigned v = __hip_atomic_load(p, __ATOMIC_RELAXED, __HIP_MEMORY_SCOPE_AGENT);
    if (__all(v >= target)) break;
    __builtin_amdgcn_s_sleep(1);
  }
}

// one fused, tag-validated bulk load attempt (R6 addressing: [rec][b], 8B recs)
template<int NKS>
__device__ __forceinline__ bool try_load(const ull* __restrict__ sl, int b,
                                         int quad, int k0s, unsigned want,
                                         s8v* __restrict__ bf)
{
  ull d[NKS][4];
  #pragma unroll
  for (int ks = 0; ks < NKS; ++ks){
    const int e = k0s + ks*4 + quad;
    const ull* p = sl + (long)(4*e)*64 + b;
    #pragma unroll
    for (int i = 0; i < 4; ++i)
      d[ks][i] = __hip_atomic_load(p + (long)i*64, __ATOMIC_RELAXED, __HIP_MEMORY_SCOPE_AGENT);
  }
  bool ok = true;
  #pragma unroll
  for (int ks = 0; ks < NKS; ++ks)
    #pragma unroll
    for (int i = 0; i < 4; ++i)
      ok = ok && ((unsigned)(d[ks][i] >> 32) == want);
  if (!__all(ok)) return false;
  #pragma unroll
  for (int ks = 0; ks < NKS; ++ks){
    s8v v;
    #pragma unroll
    for (int i = 0; i < 4; ++i){
      unsigned lo = (unsigned)d[ks][i];
      v[2*i]   = (short)(lo & 0xFFFFu);
      v[2*i+1] = (short)(lo >> 16);
    }
    bf[ks] = v;
  }
  return true;
}

// =====================================================================
// scan body: one wave's role for the whole 512-tick loop.
// ROLE: 0 = xe input (plain loads), 1 = self-layer hidden (slot (t-1)&mask,
//       want t, flag-poll first), 2 = cross h0 input (slot t, want t+1,
//       speculative load first — producer layer runs ahead)
// =====================================================================
template<int NKS, int ROLE>
__device__ __forceinline__ void scan_body(
    int isL1, int rowWG, int bh, int wave, int lane, int j0, int b0,
    const s8v* __restrict__ Whi, const s8v* __restrict__ Wlo, int AKs, int k0s,
    const s8v* __restrict__ xsrc,
    const ull* __restrict__ rsrc, int slotMask,
    const float* __restrict__ bih, const float* __restrict__ bhh,
    ull* __restrict__ rout, int outMask,
    char* __restrict__ ws, f4v* __restrict__ part, unsigned* __restrict__ cnt)
{
  const int quad = lane >> 4, col = lane & 15;

  // ---- A fragments (hi + lo), resident across all 512 ticks ----
  s8v ahi[3][NKS], alo[3][NKS];
  #pragma unroll
  for (int rt = 0; rt < 3; ++rt){
    const int row = rt*512 + j0 + col;
    #pragma unroll
    for (int ks = 0; ks < NKS; ++ks){
      const int e = row*AKs + k0s + ks*4 + quad;
      ahi[rt][ks] = Whi[e];
      alo[rt][ks] = Wlo[e];
    }
  }

  // ---- per-thread gate constants + persistent fp32 h (lane<32) ----
  float cr[4], cz[4], cnx[4], cnh[4], hp[4];
  #pragma unroll
  for (int r4 = 0; r4 < 4; ++r4){
    int j = j0 + wave*4 + r4;
    cr[r4]  = bih[j]      + bhh[j];
    cz[r4]  = bih[512+j]  + bhh[512+j];
    cnx[r4] = bih[1024+j];
    cnh[r4] = bhh[1024+j];
    hp[r4]  = 0.f;
  }

  const int pollLayer = (ROLE == 2) ? 0 : isL1;
  const unsigned* flg = (const unsigned*)(ws + FLG_OFF)
                        + ((pollLayer*2 + bh)*4 + (rowWG & 3))*32;
  unsigned* fpub = (unsigned*)(ws + FLG_OFF) + ((isL1*2 + bh)*4)*32 + rowWG;

  for (int t = 0; t < S_LEN; ++t){
    f4v acc[3][2];
    #pragma unroll
    for (int rt = 0; rt < 3; ++rt){ acc[rt][0] = (f4v)0.f; acc[rt][1] = (f4v)0.f; }

    if (ROLE == 0){
      // ---- plain xe input (pre-converted, no tags) ----
      #pragma unroll
      for (int ct = 0; ct < 2; ++ct){
        const int nG = b0 + ct*16 + col;
        const long base = ((long)t*64 + nG)*32 + k0s + quad;
        s8v bf[NKS];
        #pragma unroll
        for (int ks = 0; ks < NKS; ++ks) bf[ks] = xsrc[base + ks*4];
        #pragma unroll
        for (int ks = 0; ks < NKS; ++ks)
          #pragma unroll
          for (int rt = 0; rt < 3; ++rt){
            acc[rt][ct] = __builtin_amdgcn_mfma_f32_16x16x32_bf16(ahi[rt][ks], bf[ks], acc[rt][ct], 0, 0, 0);
            acc[rt][ct] = __builtin_amdgcn_mfma_f32_16x16x32_bf16(alo[rt][ks], bf[ks], acc[rt][ct], 0, 0, 0);
          }
      }
    } else if ((ROLE != 1) || (t > 0)){
      const int slot = (ROLE == 1) ? ((t-1) & slotMask) : (t & slotMask);
      const unsigned want = (ROLE == 1) ? (unsigned)t : (unsigned)(t+1);
      const ull* sl = rsrc + (long)slot*16384;
      #pragma unroll
      for (int ct = 0; ct < 2; ++ct){
        const int b = b0 + ct*16 + col;
        s8v bf[NKS];
        if (ROLE == 2){
          // speculative (producer layer runs ahead; usually ready)
          if (!try_load<NKS>(sl, b, quad, k0s, want, bf)){
            hint_wait(flg, lane, want);
            while (!try_load<NKS>(sl, b, quad, k0s, want, bf))
              __builtin_amdgcn_s_sleep(1);
          }
        } else {
          if (ct == 0) hint_wait(flg, lane, want);
          while (!try_load<NKS>(sl, b, quad, k0s, want, bf))
            __builtin_amdgcn_s_sleep(1);
        }
        #pragma unroll
        for (int ks = 0; ks < NKS; ++ks)
          #pragma unroll
          for (int rt = 0; rt < 3; ++rt){
            acc[rt][ct] = __builtin_amdgcn_mfma_f32_16x16x32_bf16(ahi[rt][ks], bf[ks], acc[rt][ct], 0, 0, 0);
            acc[rt][ct] = __builtin_amdgcn_mfma_f32_16x16x32_bf16(alo[rt][ks], bf[ks], acc[rt][ct], 0, 0, 0);
          }
      }
    }

    // ---- partials to LDS (double-buffered: one barrier per tick) ----
    const int pb = t & 1;
    #pragma unroll
    for (int rt = 0; rt < 3; ++rt)
      #pragma unroll
      for (int ct = 0; ct < 2; ++ct)
        part[((pb*4 + wave)*6 + rt*2 + ct)*64 + lane] = acc[rt][ct];
    __syncthreads();

    // ---- reduce + gate math + tagged h store (wave = unit-group, lane<32 = b) ----
    if (lane < 32){
      const int b = lane;
      const int pl = wave*16 + (b & 15);
      const int ct = b >> 4;
      f4v sr = (f4v)0.f, sz = (f4v)0.f, snx = (f4v)0.f, snh = (f4v)0.f;
      #pragma unroll
      for (int w = 0; w < 4; ++w){
        const bool inpW = isL1 ? (w < 2) : (w >= 2);
        f4v g0 = part[((pb*4 + w)*6 + 0*2 + ct)*64 + pl];
        f4v g1 = part[((pb*4 + w)*6 + 1*2 + ct)*64 + pl];
        f4v g2 = part[((pb*4 + w)*6 + 2*2 + ct)*64 + pl];
        sr += g0; sz += g1;
        if (inpW) snx += g2; else snh += g2;
      }
      unsigned short hb[4];
      #pragma unroll
      for (int r4 = 0; r4 < 4; ++r4){
        float r = sigm(sr[r4] + cr[r4]);
        float z = sigm(sz[r4] + cz[r4]);
        float n = tanhx(snx[r4] + cnx[r4] + r*(snh[r4] + cnh[r4]));
        float h = n + z*(hp[r4] - n);
        hp[r4] = h;
        hb[r4] = f2bf(h);
      }
      const int slotw = t & outMask;
      const ull tg = ((ull)(unsigned)(t + 1)) << 32;
      ull* ob = rout + (long)slotw*16384 + (long)(rowWG*8 + wave*2)*64 + (b0 + b);
      st_rec(ob,      ((ull)((unsigned)hb[0] | ((unsigned)hb[1] << 16))) | tg);
      st_rec(ob + 64, ((ull)((unsigned)hb[2] | ((unsigned)hb[3] << 16))) | tg);
    }
    // ---- last-arriving wave publishes the hint flag (no drain, no barrier) ----
    if (lane == 0){
      unsigned old = atomicAdd(cnt, 1u);
      if (old == 4u*(unsigned)t + 3u){
        #pragma unroll
        for (int rp = 0; rp < 4; ++rp)
          __hip_atomic_store(fpub + rp*32, (unsigned)(t + 1),
                             __ATOMIC_RELAXED, __HIP_MEMORY_SCOPE_AGENT);
      }
    }
  }
}

// =====================================================================
// Persistent MFMA scan kernel: 128 WGs.
// wg 0..63: layer0, wg 64..127: layer1. lw=wg&63: rowWG=lw>>1, bh=lw&1.
// L0: waves 0-1 hidden (h0), waves 2-3 xe input. L1: waves 0-1 input (h0
// cross, speculative), waves 2-3 hidden (h1, 4-slot ring).
// =====================================================================
__global__ __launch_bounds__(TPB, 1) void gru_mfma_kernel(
    const float* __restrict__ bih0, const float* __restrict__ bhh0,
    const float* __restrict__ bih1, const float* __restrict__ bhh1,
    const float* __restrict__ Wfc,  const float* __restrict__ bfc,
    float* __restrict__ out, char* __restrict__ ws)
{
  __shared__ f4v part[3072];                   // 48 KB double-buffered partials
  __shared__ unsigned cnt;                     // per-tick wave-arrival counter

  const int tid  = threadIdx.x;
  const int wg   = blockIdx.x;
  const int lane = tid & 63;
  const int wave = tid >> 6;
  const int isL1 = (wg >= 64);
  const int lw   = wg & 63;
  const int rowWG = lw >> 1;
  const int bh    = lw & 1;
  const int j0 = rowWG * 16;
  const int b0 = bh * 32;

  if (tid == 0) cnt = 0;
  __syncthreads();

  const s8v* wi0h = (const s8v*)(ws + WI0H_OFF); const s8v* wi0l = (const s8v*)(ws + WI0L_OFF);
  const s8v* wh0h = (const s8v*)(ws + WH0H_OFF); const s8v* wh0l = (const s8v*)(ws + WH0L_OFF);
  const s8v* wi1h = (const s8v*)(ws + WI1H_OFF); const s8v* wi1l = (const s8v*)(ws + WI1L_OFF);
  const s8v* wh1h = (const s8v*)(ws + WH1H_OFF); const s8v* wh1l = (const s8v*)(ws + WH1L_OFF);
  const s8v* xeb = (const s8v*)(ws + XEB_OFF);
  const ull* h0r = (const ull*)(ws + H0R_OFF);
  const ull* h1r = (const ull*)(ws + H1R_OFF);
  ull* h0w = (ull*)(ws + H0R_OFF);
  ull* h1w = (ull*)(ws + H1R_OFF);

  if (!isL1){
    if (wave < 2)
      scan_body<8,1>(isL1, rowWG, bh, wave, lane, j0, b0,
                     wh0h, wh0l, 64, wave*32, xeb, h0r, 0x3FFFFFFF,
                     bih0, bhh0, h0w, 0x3FFFFFFF, ws, part, &cnt);
    else
      scan_body<4,0>(isL1, rowWG, bh, wave, lane, j0, b0,
                     wi0h, wi0l, 32, (wave-2)*16, xeb, h0r, 0x3FFFFFFF,
                     bih0, bhh0, h0w, 0x3FFFFFFF, ws, part, &cnt);
  } else {
    if (wave < 2)
      scan_body<8,2>(isL1, rowWG, bh, wave, lane, j0, b0,
                     wi1h, wi1l, 64, wave*32, xeb, h0r, 0x3FFFFFFF,
                     bih1, bhh1, h1w, 3, ws, part, &cnt);
    else
      scan_body<8,1>(isL1, rowWG, bh, wave, lane, j0, b0,
                     wh1h, wh1l, 64, (wave-2)*32, xeb, h1r, 3,
                     bih1, bhh1, h1w, 3, ws, part, &cnt);
  }

  // ---- epilogue FC: out[b] = sigmoid(h1_511 . Wfc + bfc), tag-validated ----
  if (wg == 64 && wave == 0){
    const ull* sl = h1r + 3L*16384;            // slot 511 & 3 == 3, tag 512
    float acc = bfc[0];
    for (int c0 = 0; c0 < 256; c0 += 32){
      ull d[32];
      for (;;){
        #pragma unroll
        for (int i = 0; i < 32; ++i)
          d[i] = __hip_atomic_load(sl + (long)(c0+i)*64 + lane,
                                   __ATOMIC_RELAXED, __HIP_MEMORY_SCOPE_AGENT);
        bool ok = true;
        #pragma unroll
        for (int i = 0; i < 32; ++i) ok = ok && ((unsigned)(d[i] >> 32) == 512u);
        if (__all(ok)) break;
        __builtin_amdgcn_s_sleep(1);
      }
      #pragma unroll
      for (int i = 0; i < 32; ++i){
        unsigned lo = (unsigned)d[i];
        int u = (c0 + i) * 2;
        acc += bf2f((unsigned short)(lo & 0xFFFFu)) * Wfc[u]
             + bf2f((unsigned short)(lo >> 16))     * Wfc[u+1];
      }
    }
    out[lane] = sigm(acc);
  }
}

// =====================================================================
// FALLBACK (R1 fence path) — only if ws too small for the fast path.
// =====================================================================
__global__ void gather_xe_kernel(const int* __restrict__ x,
                                 const float* __restrict__ emb,
                                 float4* __restrict__ xe4)
{
  int idx = blockIdx.x * TPB + threadIdx.x;
  int b  = idx & 63;
  int k4 = (idx >> 6) & 63;
  int t  = idx >> 12;
  int tok = x[b * S_LEN + t];
  float4 v = make_float4(0.f, 0.f, 0.f, 0.f);
  if (tok != 0) v = ((const float4*)emb)[(size_t)tok * 64 + k4];
  xe4[idx] = v;
}

__device__ __forceinline__ void accum_vec(const float4* __restrict__ xin,
                                          const float4* __restrict__ w0,
                                          const float4* __restrict__ w1,
                                          const float4* __restrict__ w2,
                                          int n4, int lane,
                                          float& ar, float& az, float& an)
{
  #pragma unroll 4
  for (int k = 0; k < n4; ++k){
    float4 xv = xin[k * 64 + lane];
    float4 wr = w0[k], wz = w1[k], wn = w2[k];
    ar = fmaf(xv.x, wr.x, ar); az = fmaf(xv.x, wz.x, az); an = fmaf(xv.x, wn.x, an);
    ar = fmaf(xv.y, wr.y, ar); az = fmaf(xv.y, wz.y, az); an = fmaf(xv.y, wn.y, an);
    ar = fmaf(xv.z, wr.z, ar); az = fmaf(xv.z, wz.z, az); an = fmaf(xv.z, wn.z, an);
    ar = fmaf(xv.w, wr.w, ar); az = fmaf(xv.w, wz.w, az); an = fmaf(xv.w, wn.w, an);
  }
}

__device__ __forceinline__ void accum_emb(const int* __restrict__ x,
                                          const float* __restrict__ emb, int t,
                                          const float4* __restrict__ w0,
                                          const float4* __restrict__ w1,
                                          const float4* __restrict__ w2,
                                          int lane, float& ar, float& az, float& an)
{
  int tok = x[lane * S_LEN + t];
  const float4* erow = (const float4*)emb + (size_t)tok * 64;
  float m = (tok != 0) ? 1.0f : 0.0f;
  #pragma unroll 4
  for (int k = 0; k < 64; ++k){
    float4 xv = erow[k];
    float xx = xv.x*m, xy = xv.y*m, xz = xv.z*m, xw = xv.w*m;
    float4 wr = w0[k], wz = w1[k], wn = w2[k];
    ar = fmaf(xx, wr.x, ar); az = fmaf(xx, wz.x, az); an = fmaf(xx, wn.x, an);
    ar = fmaf(xy, wr.y, ar); az = fmaf(xy, wz.y, az); an = fmaf(xy, wn.y, an);
    ar = fmaf(xz, wr.z, ar); az = fmaf(xz, wz.z, az); an = fmaf(xz, wn.z, an);
    ar = fmaf(xw, wr.w, ar); az = fmaf(xw, wz.w, az); an = fmaf(xw, wn.w, an);
  }
}

__device__ __forceinline__ void stage_weights(float4* wlds, int tid, int j0, int kin4,
                                              const float* Wih, const float* Whh)
{
  const int per = 3 * (kin4 + 128);
  for (int idx = tid; idx < 4 * per; idx += TPB){
    int w = idx / per, rem = idx - w * per;
    int g = rem / (kin4 + 128), k = rem - g * (kin4 + 128);
    int row = g * HID + j0 + w;
    float4 v;
    if (k < kin4) v = ((const float4*)Wih)[(size_t)row * kin4 + k];
    else          v = ((const float4*)Whh)[(size_t)row * 128 + (k - kin4)];
    wlds[(w * 3 + g) * 256 + k] = v;
  }
}

__device__ __forceinline__ void barrier_tick(int* bar, int wg, int tid, int phase)
{
  __syncthreads();
  if (tid == 0){
    __builtin_amdgcn_fence(__ATOMIC_RELEASE, "agent");
    int* leaf = bar + 32 + (wg >> 4) * 32;
    int old = __hip_atomic_fetch_add(leaf, 1, __ATOMIC_ACQ_REL, __HIP_MEMORY_SCOPE_AGENT);
    if (old == phase * 16 + 15){
      __hip_atomic_fetch_add(bar, 1, __ATOMIC_ACQ_REL, __HIP_MEMORY_SCOPE_AGENT);
    }
    const int target = (phase + 1) * 16;
    while (__hip_atomic_load(bar, __ATOMIC_ACQUIRE, __HIP_MEMORY_SCOPE_AGENT) < target){
      __builtin_amdgcn_s_sleep(2);
    }
    __builtin_amdgcn_fence(__ATOMIC_ACQUIRE, "agent");
  }
  __syncthreads();
}

__device__ __forceinline__ void finish_store(const float4* __restrict__ hprev,
                                             float ar, float az, float anx, float anh,
                                             int lane, int j, float4* __restrict__ hout)
{
  float r  = sigmoid_f(ar);
  float zz = sigmoid_f(az);
  float n  = tanhf(fmaf(r, anh, anx));
  int fi = ((j >> 2) * 64 + lane) * 4 + (j & 3);
  float hhp = ((const float*)hprev)[fi];
  ((float*)hout)[fi] = fmaf(zz, hhp - n, n);
}

__global__ __launch_bounds__(TPB) void gru_persist_kernel(
    const int*   __restrict__ x,    const float* __restrict__ emb,
    const float* __restrict__ Wih0, const float* __restrict__ Whh0,
    const float* __restrict__ bih0, const float* __restrict__ bhh0,
    const float* __restrict__ Wih1, const float* __restrict__ Whh1,
    const float* __restrict__ bih1, const float* __restrict__ bhh1,
    const float* __restrict__ Wfc,  const float* __restrict__ bfc,
    float* __restrict__ out, int* __restrict__ bar,
    float4* __restrict__ A0, float4* __restrict__ A1,
    float4* __restrict__ B0, float4* __restrict__ B1,
    const float4* __restrict__ xe4, int use_xe)
{
  __shared__ float4 wlds[3072];
  const int tid  = threadIdx.x;
  const int wg   = blockIdx.x;
  const int lane = tid & 63;
  const int wave = tid >> 6;
  const bool isL1 = (wg >= 128);
  const int j0   = (isL1 ? wg - 128 : wg) * 4;
  const int kin4 = isL1 ? 128 : 64;

  stage_weights(wlds, tid, j0, kin4, isL1 ? Wih1 : Wih0, isL1 ? Whh1 : Whh0);
  __syncthreads();

  const int j = j0 + wave;
  const float* bih = isL1 ? bih1 : bih0;
  const float* bhh = isL1 ? bhh1 : bhh0;
  const float br  = bih[j]        + bhh[j];
  const float bz  = bih[j + 512]  + bhh[j + 512];
  const float bnx = bih[j + 1024];
  const float bnh = bhh[j + 1024];

  const float4* w0 = &wlds[(wave * 3 + 0) * 256];
  const float4* w1 = &wlds[(wave * 3 + 1) * 256];
  const float4* w2 = &wlds[(wave * 3 + 2) * 256];

  float4* A[2] = {A0, A1};
  float4* B[2] = {B0, B1};

  for (int t = 0; t <= S_LEN; ++t){
    if (!isL1){
      if (t < S_LEN){
        const float4* hprev = A[(t + 1) & 1];
        float ar = br, az = bz, anx = bnx, anh = bnh;
        if (use_xe) accum_vec(xe4 + (size_t)t * 4096, w0, w1, w2, 64, lane, ar, az, anx);
        else        accum_emb(x, emb, t, w0, w1, w2, lane, ar, az, anx);
        accum_vec(hprev, w0 + 64, w1 + 64, w2 + 64, 128, lane, ar, az, anh);
        finish_store(hprev, ar, az, anx, anh, lane, j, A[t & 1]);
      }
    } else if (t >= 1){
      const int u = t - 1;
      const float4* xin   = A[u & 1];
      const float4* hprev = B[(u + 1) & 1];
      float ar = br, az = bz, anx = bnx, anh = bnh;
      accum_vec(xin,   w0,       w1,       w2,       128, lane, ar, az, anx);
      accum_vec(hprev, w0 + 128, w1 + 128, w2 + 128, 128, lane, ar, az, anh);
      finish_store(hprev, ar, az, anx, anh, lane, j, B[u & 1]);
    }
    barrier_tick(bar, wg, tid, t);
  }

  if (wg == 0 && wave == 0){
    float acc = bfc[0];
    const float4* h1 = B[1];
    const float4* wf = (const float4*)Wfc;
    #pragma unroll 4
    for (int k = 0; k < 128; ++k){
      float4 hv = h1[k * 64 + lane];
      float4 wv = wf[k];
      acc = fmaf(hv.x, wv.x, acc); acc = fmaf(hv.y, wv.y, acc);
      acc = fmaf(hv.z, wv.z, acc); acc = fmaf(hv.w, wv.w, acc);
    }
    out[lane] = sigmoid_f(acc);
  }
}

extern "C" void kernel_launch(void* const* d_in, const int* in_sizes, int n_in,
                              void* d_out, int out_size, void* d_ws, size_t ws_size,
                              hipStream_t stream)
{
  (void)in_sizes; (void)n_in; (void)out_size;
  const int*   x    = (const int*)  d_in[0];
  const float* emb  = (const float*)d_in[1];
  const float* Wih0 = (const float*)d_in[2];
  const float* Whh0 = (const float*)d_in[3];
  const float* bih0 = (const float*)d_in[4];
  const float* bhh0 = (const float*)d_in[5];
  const float* Wih1 = (const float*)d_in[6];
  const float* Whh1 = (const float*)d_in[7];
  const float* bih1 = (const float*)d_in[8];
  const float* bhh1 = (const float*)d_in[9];
  const float* Wfc  = (const float*)d_in[10];
  const float* bfc  = (const float*)d_in[11];
  float* out = (float*)d_out;
  char* ws = (char*)d_ws;

  if (ws_size >= (size_t)NEED_FAST){
    // zero hint flags (2 KB); data records self-validate against 0xAA poison
    hipMemsetAsync(ws + FLG_OFF, 0, 2048, stream);
    wcvt_kernel<<<2752512 / TPB, TPB, 0, stream>>>(Wih0, Whh0, Wih1, Whh1, ws);
    gather_xe_bf_kernel<<<2097152 / TPB, TPB, 0, stream>>>(x, emb, ws);
    gru_mfma_kernel<<<128, TPB, 0, stream>>>(bih0, bhh0, bih1, bhh1, Wfc, bfc, out, ws);
  } else {
    int*    bar = (int*)ws;
    float4* A0  = (float4*)(ws + A_OFF);
    float4* A1  = (float4*)(ws + A_OFF + HBUF_BYTES);
    float4* B0  = (float4*)(ws + B_OFF);
    float4* B1  = (float4*)(ws + B_OFF + HBUF_BYTES);
    float4* xe4 = (float4*)(ws + XE_OFF);
    const int use_xe = (ws_size >= (size_t)XE_OFF + XE_BYTES) ? 1 : 0;
    hipMemsetAsync(ws, 0, XE_OFF, stream);
    if (use_xe){
      gather_xe_kernel<<<(S_LEN * 64 * BATCH) / TPB, TPB, 0, stream>>>(x, emb, xe4);
    }
    gru_persist_kernel<<<256, TPB, 0, stream>>>(
        x, emb, Wih0, Whh0, bih0, bhh0, Wih1, Whh1, bih1, bhh1, Wfc, bfc,
        out, bar, A0, A1, B0, B1, xe4, use_xe);
  }
}

// Round 9
// 2550.203 us; speedup vs baseline: 1.2696x; 1.0512x over previous
//
#include <hip/hip_runtime.h>
#include <math.h>

typedef short  s8v __attribute__((ext_vector_type(8)));   // 8 bf16 (4 VGPRs)
typedef float  f4v __attribute__((ext_vector_type(4)));
typedef unsigned long long ull;

#define S_LEN 512
#define BATCH 64
#define HID   512
#define TPB   256

// ---------------- fast-path workspace layout (R6) ----------------
// h record = 8B {2 x bf16 | tag = tick+1}, layout [slot][rec 256][b 64]
#define WI0H_OFF 0L
#define WI0L_OFF 786432L
#define WH0H_OFF 1572864L
#define WH0L_OFF 3145728L
#define WI1H_OFF 4718592L
#define WI1L_OFF 6291456L
#define WH1H_OFF 7864320L
#define WH1L_OFF 9437184L
#define XEB_OFF  11010048L                   // xe bf16 [t*64+b][256]
#define H0R_OFF  27787264L                   // 512 slots x 16384 ull
#define H1R_OFF  94896128L                   // 4 slots x 16384 ull (ring, lag proof)
#define NEED_FAST 95420416L

// ---------------- fallback (fence path, R1) layout ----------------
#define BAR_BYTES   4096
#define HBUF_BYTES  (HID*BATCH*4)
#define A_OFF       BAR_BYTES
#define B_OFF       (A_OFF + 2*HBUF_BYTES)
#define XE_OFF      (B_OFF + 2*HBUF_BYTES)
#define XE_BYTES    ((size_t)S_LEN*64*BATCH*16)

__device__ __forceinline__ float fexp2(float x){ return __builtin_amdgcn_exp2f(x); }
__device__ __forceinline__ float frcp (float x){ return __builtin_amdgcn_rcpf(x); }
__device__ __forceinline__ float sigm (float x){ return frcp(1.f + fexp2(-1.44269504089f*x)); }
__device__ __forceinline__ float tanhx(float x){ return 1.f - 2.f*frcp(1.f + fexp2(2.88539008178f*x)); }
__device__ __forceinline__ float sigmoid_f(float v){ return 1.0f/(1.0f + expf(-v)); }

__device__ __forceinline__ unsigned short f2bf(float f){
  unsigned int u = __float_as_uint(f);
  u = u + 0x7FFFu + ((u >> 16) & 1u);          // RNE
  return (unsigned short)(u >> 16);
}
__device__ __forceinline__ float bf2f(unsigned short s){
  return __uint_as_float(((unsigned int)s) << 16);
}

// =====================================================================
// Phase A kernels
// =====================================================================
__global__ void wcvt_kernel(const float* __restrict__ Wih0, const float* __restrict__ Whh0,
                            const float* __restrict__ Wih1, const float* __restrict__ Whh1,
                            char* __restrict__ ws)
{
  int idx = blockIdx.x * TPB + threadIdx.x;    // 2,752,512 total
  const float* src; long hi_off, lo_off; int pos;
  if (idx < 393216)       { src = Wih0; pos = idx;           hi_off = WI0H_OFF; lo_off = WI0L_OFF; }
  else if (idx < 1179648) { src = Whh0; pos = idx - 393216;  hi_off = WH0H_OFF; lo_off = WH0L_OFF; }
  else if (idx < 1966080) { src = Wih1; pos = idx - 1179648; hi_off = WI1H_OFF; lo_off = WI1L_OFF; }
  else                    { src = Whh1; pos = idx - 1966080; hi_off = WH1H_OFF; lo_off = WH1L_OFF; }
  float w = src[pos];
  unsigned short h = f2bf(w);
  unsigned short l = f2bf(w - bf2f(h));
  ((unsigned short*)(ws + hi_off))[pos] = h;
  ((unsigned short*)(ws + lo_off))[pos] = l;
}

__global__ void gather_xe_bf_kernel(const int* __restrict__ x,
                                    const float* __restrict__ emb,
                                    char* __restrict__ ws)
{
  int idx = blockIdx.x * TPB + threadIdx.x;    // 2,097,152 = 32768 n * 64 k4
  int k4 = idx & 63;
  int n  = idx >> 6;
  int t = n >> 6, b = n & 63;
  int tok = x[b * S_LEN + t];
  float4 v = make_float4(0.f,0.f,0.f,0.f);
  if (tok != 0) v = ((const float4*)emb)[(size_t)tok * 64 + k4];
  unsigned int lo = (unsigned int)f2bf(v.x) | ((unsigned int)f2bf(v.y) << 16);
  unsigned int hi = (unsigned int)f2bf(v.z) | ((unsigned int)f2bf(v.w) << 16);
  ((uint2*)(ws + XEB_OFF))[(long)n * 64 + k4] = make_uint2(lo, hi);
}

// =====================================================================
// Tagged-record primitives (R6 layout [slot][rec][b], 8B records).
// =====================================================================
__device__ __forceinline__ void st_rec(ull* p, ull v){
  __hip_atomic_store(p, v, __ATOMIC_RELAXED, __HIP_MEMORY_SCOPE_AGENT);
}

// cheap subset poll: one 8B tagged load/lane sampling all 64 rec-rows
// (recs [recBase, recBase+64)) x 32 b of the wave's slice — a HINT only;
// the fused bulk load below revalidates every record it consumes.
__device__ __forceinline__ void poll_slice(const ull* __restrict__ sl, int recBase,
                                           int b0, int lane, unsigned want){
  const ull* p = sl + (long)(recBase + lane)*64 + (b0 + (lane & 31));
  for (;;){
    ull v = __hip_atomic_load(p, __ATOMIC_RELAXED, __HIP_MEMORY_SCOPE_AGENT);
    if (__all((unsigned)(v >> 32) == want)) break;
    __builtin_amdgcn_s_sleep(1);
  }
}

// fused, tag-validated bulk load attempt
template<int NKS>
__device__ __forceinline__ bool try_load(const ull* __restrict__ sl, int b,
                                         int quad, int k0s, unsigned want,
                                         s8v* __restrict__ bf)
{
  ull d[NKS][4];
  #pragma unroll
  for (int ks = 0; ks < NKS; ++ks){
    const int e = k0s + ks*4 + quad;
    const ull* p = sl + (long)(4*e)*64 + b;
    #pragma unroll
    for (int i = 0; i < 4; ++i)
      d[ks][i] = __hip_atomic_load(p + (long)i*64, __ATOMIC_RELAXED, __HIP_MEMORY_SCOPE_AGENT);
  }
  bool ok = true;
  #pragma unroll
  for (int ks = 0; ks < NKS; ++ks)
    #pragma unroll
    for (int i = 0; i < 4; ++i)
      ok = ok && ((unsigned)(d[ks][i] >> 32) == want);
  if (!__all(ok)) return false;
  #pragma unroll
  for (int ks = 0; ks < NKS; ++ks){
    s8v v;
    #pragma unroll
    for (int i = 0; i < 4; ++i){
      unsigned lo = (unsigned)d[ks][i];
      v[2*i]   = (short)(lo & 0xFFFFu);
      v[2*i+1] = (short)(lo >> 16);
    }
    bf[ks] = v;
  }
  return true;
}

#define MF(A,B,C) __builtin_amdgcn_mfma_f32_16x16x32_bf16((A),(B),(C),0,0,0)

// =====================================================================
// Symmetric scan body: EVERY wave handles a K-quarter of input + a
// K-quarter of hidden. Input MFMA issues before the self-chain wait.
// acc comps: 0=r (in+hid), 1=z (in+hid), 2=n-input, 3=n-hidden.
// =====================================================================
template<int NKSI, int LAYER>
__device__ __forceinline__ void scan_body(
    int rowWG, int bh, int wave, int lane, int j0, int b0,
    const s8v* __restrict__ Wih_hi, const s8v* __restrict__ Wih_lo, int AKi,
    const s8v* __restrict__ Whh_hi, const s8v* __restrict__ Whh_lo,
    const s8v* __restrict__ xeb,
    const ull* __restrict__ insrc,          // h0 records (LAYER==1)
    const ull* __restrict__ hsrc, int hMask,
    const float* __restrict__ bih, const float* __restrict__ bhh,
    ull* __restrict__ rout, int outMask,
    f4v* __restrict__ part)
{
  const int quad = lane >> 4, col = lane & 15;
  const int k0i = wave * (NKSI*4);             // input K-slice (s8v units)
  const int k0h = wave * 16;                   // hidden K-slice (NKSH=4)

  // ---- A fragments (hi + lo), resident across all 512 ticks ----
  s8v aih[3][NKSI], ail[3][NKSI], ahh[3][4], ahl[3][4];
  #pragma unroll
  for (int rt = 0; rt < 3; ++rt){
    const int row = rt*512 + j0 + col;
    #pragma unroll
    for (int ks = 0; ks < NKSI; ++ks){
      const int e = row*AKi + k0i + ks*4 + quad;
      aih[rt][ks] = Wih_hi[e];
      ail[rt][ks] = Wih_lo[e];
    }
    #pragma unroll
    for (int ks = 0; ks < 4; ++ks){
      const int e = row*64 + k0h + ks*4 + quad;
      ahh[rt][ks] = Whh_hi[e];
      ahl[rt][ks] = Whh_lo[e];
    }
  }

  // ---- per-thread gate constants + persistent fp32 h (lane<32) ----
  float cr[4], cz[4], cnx[4], cnh[4], hp[4];
  #pragma unroll
  for (int r4 = 0; r4 < 4; ++r4){
    int j = j0 + wave*4 + r4;
    cr[r4]  = bih[j]      + bhh[j];
    cz[r4]  = bih[512+j]  + bhh[512+j];
    cnx[r4] = bih[1024+j];
    cnh[r4] = bhh[1024+j];
    hp[r4]  = 0.f;
  }

  for (int t = 0; t < S_LEN; ++t){
    f4v acc[4][2];
    #pragma unroll
    for (int c = 0; c < 4; ++c){ acc[c][0] = (f4v)0.f; acc[c][1] = (f4v)0.f; }

    // ---- input part (before the self-chain wait) ----
    if (LAYER == 0){
      #pragma unroll
      for (int ct = 0; ct < 2; ++ct){
        const int nG = b0 + ct*16 + col;
        const long base = ((long)t*64 + nG)*32 + k0i + quad;
        s8v bf[NKSI];
        #pragma unroll
        for (int ks = 0; ks < NKSI; ++ks) bf[ks] = xeb[base + ks*4];
        #pragma unroll
        for (int ks = 0; ks < NKSI; ++ks){
          acc[0][ct] = MF(aih[0][ks], bf[ks], acc[0][ct]);
          acc[0][ct] = MF(ail[0][ks], bf[ks], acc[0][ct]);
          acc[1][ct] = MF(aih[1][ks], bf[ks], acc[1][ct]);
          acc[1][ct] = MF(ail[1][ks], bf[ks], acc[1][ct]);
          acc[2][ct] = MF(aih[2][ks], bf[ks], acc[2][ct]);
          acc[2][ct] = MF(ail[2][ks], bf[ks], acc[2][ct]);
        }
      }
    } else {
      const ull* sl = insrc + (long)t*16384;   // h0 slot t (write-once)
      const unsigned want = (unsigned)(t + 1);
      #pragma unroll
      for (int ct = 0; ct < 2; ++ct){
        const int b = b0 + ct*16 + col;
        s8v bf[NKSI];
        if (!try_load<NKSI>(sl, b, quad, k0i, want, bf)){   // optimistic (producer ahead)
          poll_slice(sl, 4*k0i, b0, lane, want);
          while (!try_load<NKSI>(sl, b, quad, k0i, want, bf))
            __builtin_amdgcn_s_sleep(1);
        }
        #pragma unroll
        for (int ks = 0; ks < NKSI; ++ks){
          acc[0][ct] = MF(aih[0][ks], bf[ks], acc[0][ct]);
          acc[0][ct] = MF(ail[0][ks], bf[ks], acc[0][ct]);
          acc[1][ct] = MF(aih[1][ks], bf[ks], acc[1][ct]);
          acc[1][ct] = MF(ail[1][ks], bf[ks], acc[1][ct]);
          acc[2][ct] = MF(aih[2][ks], bf[ks], acc[2][ct]);
          acc[2][ct] = MF(ail[2][ks], bf[ks], acc[2][ct]);
        }
      }
    }

    // ---- hidden part (self-chain: subset-poll then fused validated bulk) ----
    if (t > 0){
      const ull* sl = hsrc + (long)((t-1) & hMask)*16384;
      const unsigned want = (unsigned)t;
      poll_slice(sl, 4*k0h, b0, lane, want);
      #pragma unroll
      for (int ct = 0; ct < 2; ++ct){
        const int b = b0 + ct*16 + col;
        s8v bf[4];
        while (!try_load<4>(sl, b, quad, k0h, want, bf))
          __builtin_amdgcn_s_sleep(1);
        #pragma unroll
        for (int ks = 0; ks < 4; ++ks){
          acc[0][ct] = MF(ahh[0][ks], bf[ks], acc[0][ct]);
          acc[0][ct] = MF(ahl[0][ks], bf[ks], acc[0][ct]);
          acc[1][ct] = MF(ahh[1][ks], bf[ks], acc[1][ct]);
          acc[1][ct] = MF(ahl[1][ks], bf[ks], acc[1][ct]);
          acc[3][ct] = MF(ahh[2][ks], bf[ks], acc[3][ct]);
          acc[3][ct] = MF(ahl[2][ks], bf[ks], acc[3][ct]);
        }
      }
    }

    // ---- partials to LDS (double-buffered: one barrier per tick) ----
    const int pb = t & 1;
    #pragma unroll
    for (int c = 0; c < 4; ++c)
      #pragma unroll
      for (int ct = 0; ct < 2; ++ct)
        part[((pb*4 + wave)*8 + c*2 + ct)*64 + lane] = acc[c][ct];
    __syncthreads();

    // ---- reduce + gate math + tagged h store (wave = unit-group, lane<32 = b) ----
    if (lane < 32){
      const int b = lane;
      const int pl = wave*16 + (b & 15);
      const int ct = b >> 4;
      f4v sr = (f4v)0.f, sz = (f4v)0.f, snx = (f4v)0.f, snh = (f4v)0.f;
      #pragma unroll
      for (int w = 0; w < 4; ++w){
        sr  += part[((pb*4 + w)*8 + 0*2 + ct)*64 + pl];
        sz  += part[((pb*4 + w)*8 + 1*2 + ct)*64 + pl];
        snx += part[((pb*4 + w)*8 + 2*2 + ct)*64 + pl];
        snh += part[((pb*4 + w)*8 + 3*2 + ct)*64 + pl];
      }
      unsigned short hb[4];
      #pragma unroll
      for (int r4 = 0; r4 < 4; ++r4){
        float r = sigm(sr[r4] + cr[r4]);
        float z = sigm(sz[r4] + cz[r4]);
        float n = tanhx(snx[r4] + cnx[r4] + r*(snh[r4] + cnh[r4]));
        float h = n + z*(hp[r4] - n);
        hp[r4] = h;
        hb[r4] = f2bf(h);
      }
      const int slotw = t & outMask;
      const ull tg = ((ull)(unsigned)(t + 1)) << 32;
      ull* ob = rout + (long)slotw*16384 + (long)(rowWG*8 + wave*2)*64 + (b0 + b);
      st_rec(ob,      ((ull)((unsigned)hb[0] | ((unsigned)hb[1] << 16))) | tg);
      st_rec(ob + 64, ((ull)((unsigned)hb[2] | ((unsigned)hb[3] << 16))) | tg);
    }
    // no trailing barrier: next tick writes the other partial buffer
  }
}

// =====================================================================
// Persistent MFMA scan kernel: 128 WGs.
// wg 0..63: layer0, wg 64..127: layer1. lw=wg&63: rowWG=lw>>1, bh=lw&1.
// =====================================================================
__global__ __launch_bounds__(TPB, 1) void gru_mfma_kernel(
    const float* __restrict__ bih0, const float* __restrict__ bhh0,
    const float* __restrict__ bih1, const float* __restrict__ bhh1,
    const float* __restrict__ Wfc,  const float* __restrict__ bfc,
    float* __restrict__ out, char* __restrict__ ws)
{
  __shared__ f4v part[4096];                   // 64 KB double-buffered partials

  const int tid  = threadIdx.x;
  const int wg   = blockIdx.x;
  const int lane = tid & 63;
  const int wave = tid >> 6;
  const int isL1 = (wg >= 64);
  const int lw   = wg & 63;
  const int rowWG = lw >> 1;
  const int bh    = lw & 1;
  const int j0 = rowWG * 16;
  const int b0 = bh * 32;

  const s8v* wi0h = (const s8v*)(ws + WI0H_OFF); const s8v* wi0l = (const s8v*)(ws + WI0L_OFF);
  const s8v* wh0h = (const s8v*)(ws + WH0H_OFF); const s8v* wh0l = (const s8v*)(ws + WH0L_OFF);
  const s8v* wi1h = (const s8v*)(ws + WI1H_OFF); const s8v* wi1l = (const s8v*)(ws + WI1L_OFF);
  const s8v* wh1h = (const s8v*)(ws + WH1H_OFF); const s8v* wh1l = (const s8v*)(ws + WH1L_OFF);
  const s8v* xeb = (const s8v*)(ws + XEB_OFF);
  const ull* h0r = (const ull*)(ws + H0R_OFF);
  const ull* h1r = (const ull*)(ws + H1R_OFF);
  ull* h0w = (ull*)(ws + H0R_OFF);
  ull* h1w = (ull*)(ws + H1R_OFF);

  if (!isL1){
    scan_body<2,0>(rowWG, bh, wave, lane, j0, b0,
                   wi0h, wi0l, 32, wh0h, wh0l, xeb,
                   (const ull*)0, h0r, 0x3FFFFFFF,
                   bih0, bhh0, h0w, 0x3FFFFFFF, part);
  } else {
    scan_body<4,1>(rowWG, bh, wave, lane, j0, b0,
                   wi1h, wi1l, 64, wh1h, wh1l, xeb,
                   h0r, h1r, 3,
                   bih1, bhh1, h1w, 3, part);
  }

  // ---- epilogue FC: out[b] = sigmoid(h1_511 . Wfc + bfc), tag-validated ----
  if (wg == 64 && wave == 0){
    const ull* sl = h1r + 3L*16384;            // slot 511 & 3 == 3, tag 512
    float acc = bfc[0];
    for (int c0 = 0; c0 < 256; c0 += 32){
      ull d[32];
      for (;;){
        #pragma unroll
        for (int i = 0; i < 32; ++i)
          d[i] = __hip_atomic_load(sl + (long)(c0+i)*64 + lane,
                                   __ATOMIC_RELAXED, __HIP_MEMORY_SCOPE_AGENT);
        bool ok = true;
        #pragma unroll
        for (int i = 0; i < 32; ++i) ok = ok && ((unsigned)(d[i] >> 32) == 512u);
        if (__all(ok)) break;
        __builtin_amdgcn_s_sleep(1);
      }
      #pragma unroll
      for (int i = 0; i < 32; ++i){
        unsigned lo = (unsigned)d[i];
        int u = (c0 + i) * 2;
        acc += bf2f((unsigned short)(lo & 0xFFFFu)) * Wfc[u]
             + bf2f((unsigned short)(lo >> 16))     * Wfc[u+1];
      }
    }
    out[lane] = sigm(acc);
  }
}

// =====================================================================
// FALLBACK (R1 fence path) — only if ws too small for the fast path.
// =====================================================================
__global__ void gather_xe_kernel(const int* __restrict__ x,
                                 const float* __restrict__ emb,
                                 float4* __restrict__ xe4)
{
  int idx = blockIdx.x * TPB + threadIdx.x;
  int b  = idx & 63;
  int k4 = (idx >> 6) & 63;
  int t  = idx >> 12;
  int tok = x[b * S_LEN + t];
  float4 v = make_float4(0.f, 0.f, 0.f, 0.f);
  if (tok != 0) v = ((const float4*)emb)[(size_t)tok * 64 + k4];
  xe4[idx] = v;
}

__device__ __forceinline__ void accum_vec(const float4* __restrict__ xin,
                                          const float4* __restrict__ w0,
                                          const float4* __restrict__ w1,
                                          const float4* __restrict__ w2,
                                          int n4, int lane,
                                          float& ar, float& az, float& an)
{
  #pragma unroll 4
  for (int k = 0; k < n4; ++k){
    float4 xv = xin[k * 64 + lane];
    float4 wr = w0[k], wz = w1[k], wn = w2[k];
    ar = fmaf(xv.x, wr.x, ar); az = fmaf(xv.x, wz.x, az); an = fmaf(xv.x, wn.x, an);
    ar = fmaf(xv.y, wr.y, ar); az = fmaf(xv.y, wz.y, az); an = fmaf(xv.y, wn.y, an);
    ar = fmaf(xv.z, wr.z, ar); az = fmaf(xv.z, wz.z, az); an = fmaf(xv.z, wn.z, an);
    ar = fmaf(xv.w, wr.w, ar); az = fmaf(xv.w, wz.w, az); an = fmaf(xv.w, wn.w, an);
  }
}

__device__ __forceinline__ void accum_emb(const int* __restrict__ x,
                                          const float* __restrict__ emb, int t,
                                          const float4* __restrict__ w0,
                                          const float4* __restrict__ w1,
                                          const float4* __restrict__ w2,
                                          int lane, float& ar, float& az, float& an)
{
  int tok = x[lane * S_LEN + t];
  const float4* erow = (const float4*)emb + (size_t)tok * 64;
  float m = (tok != 0) ? 1.0f : 0.0f;
  #pragma unroll 4
  for (int k = 0; k < 64; ++k){
    float4 xv = erow[k];
    float xx = xv.x*m, xy = xv.y*m, xz = xv.z*m, xw = xv.w*m;
    float4 wr = w0[k], wz = w1[k], wn = w2[k];
    ar = fmaf(xx, wr.x, ar); az = fmaf(xx, wz.x, az); an = fmaf(xx, wn.x, an);
    ar = fmaf(xy, wr.y, ar); az = fmaf(xy, wz.y, az); an = fmaf(xy, wn.y, an);
    ar = fmaf(xz, wr.z, ar); az = fmaf(xz, wz.z, az); an = fmaf(xz, wn.z, an);
    ar = fmaf(xw, wr.w, ar); az = fmaf(xw, wz.w, az); an = fmaf(xw, wn.w, an);
  }
}

__device__ __forceinline__ void stage_weights(float4* wlds, int tid, int j0, int kin4,
                                              const float* Wih, const float* Whh)
{
  const int per = 3 * (kin4 + 128);
  for (int idx = tid; idx < 4 * per; idx += TPB){
    int w = idx / per, rem = idx - w * per;
    int g = rem / (kin4 + 128), k = rem - g * (kin4 + 128);
    int row = g * HID + j0 + w;
    float4 v;
    if (k < kin4) v = ((const float4*)Wih)[(size_t)row * kin4 + k];
    else          v = ((const float4*)Whh)[(size_t)row * 128 + (k - kin4)];
    wlds[(w * 3 + g) * 256 + k] = v;
  }
}

__device__ __forceinline__ void barrier_tick(int* bar, int wg, int tid, int phase)
{
  __syncthreads();
  if (tid == 0){
    __builtin_amdgcn_fence(__ATOMIC_RELEASE, "agent");
    int* leaf = bar + 32 + (wg >> 4) * 32;
    int old = __hip_atomic_fetch_add(leaf, 1, __ATOMIC_ACQ_REL, __HIP_MEMORY_SCOPE_AGENT);
    if (old == phase * 16 + 15){
      __hip_atomic_fetch_add(bar, 1, __ATOMIC_ACQ_REL, __HIP_MEMORY_SCOPE_AGENT);
    }
    const int target = (phase + 1) * 16;
    while (__hip_atomic_load(bar, __ATOMIC_ACQUIRE, __HIP_MEMORY_SCOPE_AGENT) < target){
      __builtin_amdgcn_s_sleep(2);
    }
    __builtin_amdgcn_fence(__ATOMIC_ACQUIRE, "agent");
  }
  __syncthreads();
}

__device__ __forceinline__ void finish_store(const float4* __restrict__ hprev,
                                             float ar, float az, float anx, float anh,
                                             int lane, int j, float4* __restrict__ hout)
{
  float r  = sigmoid_f(ar);
  float zz = sigmoid_f(az);
  float n  = tanhf(fmaf(r, anh, anx));
  int fi = ((j >> 2) * 64 + lane) * 4 + (j & 3);
  float hhp = ((const float*)hprev)[fi];
  ((float*)hout)[fi] = fmaf(zz, hhp - n, n);
}

__global__ __launch_bounds__(TPB) void gru_persist_kernel(
    const int*   __restrict__ x,    const float* __restrict__ emb,
    const float* __restrict__ Wih0, const float* __restrict__ Whh0,
    const float* __restrict__ bih0, const float* __restrict__ bhh0,
    const float* __restrict__ Wih1, const float* __restrict__ Whh1,
    const float* __restrict__ bih1, const float* __restrict__ bhh1,
    const float* __restrict__ Wfc,  const float* __restrict__ bfc,
    float* __restrict__ out, int* __restrict__ bar,
    float4* __restrict__ A0, float4* __restrict__ A1,
    float4* __restrict__ B0, float4* __restrict__ B1,
    const float4* __restrict__ xe4, int use_xe)
{
  __shared__ float4 wlds[3072];
  const int tid  = threadIdx.x;
  const int wg   = blockIdx.x;
  const int lane = tid & 63;
  const int wave = tid >> 6;
  const bool isL1 = (wg >= 128);
  const int j0   = (isL1 ? wg - 128 : wg) * 4;
  const int kin4 = isL1 ? 128 : 64;

  stage_weights(wlds, tid, j0, kin4, isL1 ? Wih1 : Wih0, isL1 ? Whh1 : Whh0);
  __syncthreads();

  const int j = j0 + wave;
  const float* bih = isL1 ? bih1 : bih0;
  const float* bhh = isL1 ? bhh1 : bhh0;
  const float br  = bih[j]        + bhh[j];
  const float bz  = bih[j + 512]  + bhh[j + 512];
  const float bnx = bih[j + 1024];
  const float bnh = bhh[j + 1024];

  const float4* w0 = &wlds[(wave * 3 + 0) * 256];
  const float4* w1 = &wlds[(wave * 3 + 1) * 256];
  const float4* w2 = &wlds[(wave * 3 + 2) * 256];

  float4* A[2] = {A0, A1};
  float4* B[2] = {B0, B1};

  for (int t = 0; t <= S_LEN; ++t){
    if (!isL1){
      if (t < S_LEN){
        const float4* hprev = A[(t + 1) & 1];
        float ar = br, az = bz, anx = bnx, anh = bnh;
        if (use_xe) accum_vec(xe4 + (size_t)t * 4096, w0, w1, w2, 64, lane, ar, az, anx);
        else        accum_emb(x, emb, t, w0, w1, w2, lane, ar, az, anx);
        accum_vec(hprev, w0 + 64, w1 + 64, w2 + 64, 128, lane, ar, az, anh);
        finish_store(hprev, ar, az, anx, anh, lane, j, A[t & 1]);
      }
    } else if (t >= 1){
      const int u = t - 1;
      const float4* xin   = A[u & 1];
      const float4* hprev = B[(u + 1) & 1];
      float ar = br, az = bz, anx = bnx, anh = bnh;
      accum_vec(xin,   w0,       w1,       w2,       128, lane, ar, az, anx);
      accum_vec(hprev, w0 + 128, w1 + 128, w2 + 128, 128, lane, ar, az, anh);
      finish_store(hprev, ar, az, anx, anh, lane, j, B[u & 1]);
    }
    barrier_tick(bar, wg, tid, t);
  }

  if (wg == 0 && wave == 0){
    float acc = bfc[0];
    const float4* h1 = B[1];
    const float4* wf = (const float4*)Wfc;
    #pragma unroll 4
    for (int k = 0; k < 128; ++k){
      float4 hv = h1[k * 64 + lane];
      float4 wv = wf[k];
      acc = fmaf(hv.x, wv.x, acc); acc = fmaf(hv.y, wv.y, acc);
      acc = fmaf(hv.z, wv.z, acc); acc = fmaf(hv.w, wv.w, acc);
    }
    out[lane] = sigmoid_f(acc);
  }
}

extern "C" void kernel_launch(void* const* d_in, const int* in_sizes, int n_in,
                              void* d_out, int out_size, void* d_ws, size_t ws_size,
                              hipStream_t stream)
{
  (void)in_sizes; (void)n_in; (void)out_size;
  const int*   x    = (const int*)  d_in[0];
  const float* emb  = (const float*)d_in[1];
  const float* Wih0 = (const float*)d_in[2];
  const float* Whh0 = (const float*)d_in[3];
  const float* bih0 = (const float*)d_in[4];
  const float* bhh0 = (const float*)d_in[5];
  const float* Wih1 = (const float*)d_in[6];
  const float* Whh1 = (const float*)d_in[7];
  const float* bih1 = (const float*)d_in[8];
  const float* bhh1 = (const float*)d_in[9];
  const float* Wfc  = (const float*)d_in[10];
  const float* bfc  = (const float*)d_in[11];
  float* out = (float*)d_out;
  char* ws = (char*)d_ws;

  if (ws_size >= (size_t)NEED_FAST){
    // no sync memset needed: tagged records self-validate against 0xAA poison
    wcvt_kernel<<<2752512 / TPB, TPB, 0, stream>>>(Wih0, Whh0, Wih1, Whh1, ws);
    gather_xe_bf_kernel<<<2097152 / TPB, TPB, 0, stream>>>(x, emb, ws);
    gru_mfma_kernel<<<128, TPB, 0, stream>>>(bih0, bhh0, bih1, bhh1, Wfc, bfc, out, ws);
  } else {
    int*    bar = (int*)ws;
    float4* A0  = (float4*)(ws + A_OFF);
    float4* A1  = (float4*)(ws + A_OFF + HBUF_BYTES);
    float4* B0  = (float4*)(ws + B_OFF);
    float4* B1  = (float4*)(ws + B_OFF + HBUF_BYTES);
    float4* xe4 = (float4*)(ws + XE_OFF);
    const int use_xe = (ws_size >= (size_t)XE_OFF + XE_BYTES) ? 1 : 0;
    hipMemsetAsync(ws, 0, XE_OFF, stream);
    if (use_xe){
      gather_xe_kernel<<<(S_LEN * 64 * BATCH) / TPB, TPB, 0, stream>>>(x, emb, xe4);
    }
    gru_persist_kernel<<<256, TPB, 0, stream>>>(
        x, emb, Wih0, Whh0, bih0, bhh0, Wih1, Whh1, bih1, bhh1, Wfc, bfc,
        out, bar, A0, A1, B0, B1, xe4, use_xe);
  }
}